// Round 21
// baseline (73.364 us; speedup 1.0000x reference)
//
#include <hip/hip_runtime.h>
#include <hip/hip_bf16.h>

// ---------------------------------------------------------------------------
// EdgeConvNet — Round 21: R20 + bias-in-C + DPP epilogue (DS-pipe shave).
//
// R20 (70.4us): swizzle killed bank conflicts (6.4M->0); both VALU (~57%)
// and DS (~58%) now co-limited. R21 shaves both without restructuring:
//   - fc1 bias folded into MFMA C-init (removes 16 v_add/group)
//   - epilogue xor1/xor2 via DPP quad_perm (0xB1/0x4E) and cross-quad via
//     ROW_HALF_MIRROR (0x141; valid post-quad-reduction since i^7 lands in
//     the other quad of the octet) -> 6 of 8 shuffles move DS->VALU pipe;
//     only xor32 stays on DS.
// Everything else identical to R20 (proven): 32x32x16 f16 MFMA 4-edges/tile,
// swizzled GLDS staging (conflict-free), dbuf vmcnt(2) pipeline, f16
// pre-pass, persistent 1024-block grid, (256,4).
// ---------------------------------------------------------------------------

typedef _Float16 f16x8 __attribute__((ext_vector_type(8)));
typedef _Float16 f16x4 __attribute__((ext_vector_type(4)));
typedef _Float16 f16x2 __attribute__((ext_vector_type(2)));
typedef short    bf16x8 __attribute__((ext_vector_type(8)));
typedef float    f32x4  __attribute__((ext_vector_type(4)));
typedef float    f32x2  __attribute__((ext_vector_type(2)));
typedef float    f32x16 __attribute__((ext_vector_type(16)));

union U8 { f16x8 v; f16x2 p[4]; };

static __device__ __forceinline__ short f2bf(float f) {
    union { __hip_bfloat16 h; short s; } u;
    u.h = __float2bfloat16(f);
    return u.s;
}

// DPP cross-lane add: x + x[lane ^ pattern], on the VALU pipe (no DS).
// CTRL: 0xB1 = quad_perm(1,0,3,2) -> lane^1 ; 0x4E = quad_perm(2,3,0,1) ->
// lane^2 ; 0x141 = ROW_HALF_MIRROR -> lane^7 within each octet.
template <int CTRL>
static __device__ __forceinline__ float dpp_xadd(float x) {
    union { float f; int i; } u, r;
    u.f = x;
    r.i = __builtin_amdgcn_mov_dpp(u.i, CTRL, 0xF, 0xF, false);
    return x + r.f;
}

// ---------------------------- pre-pass ------------------------------------
__global__ __launch_bounds__(256) void feat_to_f16(const float* __restrict__ in,
                                                   _Float16* __restrict__ out,
                                                   int n4) {
    int i = blockIdx.x * blockDim.x + threadIdx.x;
    const int stride = gridDim.x * blockDim.x;
    for (; i < n4; i += stride) {
        const f32x4 v = ((const f32x4*)in)[i];
        ((f16x4*)out)[i] = __builtin_convertvector(v, f16x4);
    }
}

// ------ main (persistent, 32x32 MFMA, swizzled dbuf GLDS staging) ----------
__global__ __launch_bounds__(256, 4) void edgeconv_f16_m32e(
    const _Float16* __restrict__ feat16,     // (50000, 64) f16 (in d_ws)
    const int*      __restrict__ edge_index, // (2, E) int32
    const float* __restrict__ conv_w, const float* __restrict__ conv_b,
    const float* __restrict__ w1,     const float* __restrict__ b1,
    const float* __restrict__ w2,     const float* __restrict__ b2,
    const float* __restrict__ w3,     const float* __restrict__ b3,
    float* __restrict__ out, int nEdges)
{
    // per-wave staging: [wave][buf][tile][1KB]; tile = 4 edges = 8 rows x 128B
    // row r = edge_local*2 + endpoint; LDS chunk position p holds GLOBAL
    // chunk (p + r) & 7 (swizzled source; LDS dest linear per m104)
    __shared__ __align__(16) char smem[4][2][2][1024];

    const int tid = threadIdx.x;
    const int l   = tid & 63;
    const int wid = tid >> 6;
    const int n   = l & 31;        // A row = g ; B col = et*8 + ch
    const int h   = l >> 5;        // k-half (8 elems each, K=16)
    const int ch  = n & 7;
    const int et  = n >> 3;        // edge within 4-edge tile
    // loader-side lane decomposition (1KB tile load)
    const int chunk  = l & 7;      // LDS chunk position within a 128B row
    const int rr     = l >> 3;     // row 0..7
    const int eloc   = rr >> 1;    // edge within tile
    const int endp   = rr & 1;     // 0=src 1=dst
    const int gchunk = (chunk + rr) & 7;   // swizzled GLOBAL chunk to fetch

    // A fragments: w1[g=n][k], k = j*16 + h*8 + i; rows 16..31 = 0 (R6-proven)
    f16x8 aw[4];
    #pragma unroll
    for (int j = 0; j < 4; ++j)
        #pragma unroll
        for (int i = 0; i < 8; ++i) aw[j][i] = (_Float16)0.f;
    if (n < 16) {
        const float* w1r = w1 + n * 64 + h * 8;
        #pragma unroll
        for (int j = 0; j < 4; ++j)
            #pragma unroll
            for (int i = 0; i < 8; ++i) aw[j][i] = (_Float16)w1r[j * 16 + i];
    }

    // conv params as packed-f16 splats
    const _Float16 cah = (_Float16)conv_w[2 * ch];
    const _Float16 cch = (_Float16)conv_w[2 * ch + 1];
    const _Float16 cbh = (_Float16)conv_b[ch];
    const f16x2 vca = {cah, cah}, vcc = {cch, cch}, vcb = {cbh, cbh};
    const f16x2 vzero = {(_Float16)0.f, (_Float16)0.f};

    // fc1 bias folded into MFMA C-init: acc reg r<8 holds row g =
    // (r&3) + 8*(r>>2) + 4h ; regs 8..15 are the zero A-rows (ignored)
    f32x16 accInit = {};
    float w2r[8];
    #pragma unroll
    for (int r = 0; r < 4; ++r) {
        accInit[r]     = b1[4 * h + r];      w2r[r]     = w2[4 * h + r];
        accInit[4 + r] = b1[8 + 4 * h + r];  w2r[4 + r] = w2[8 + 4 * h + r];
    }
    const float w3v = w3[ch];
    const float b2v = b2[0];
    const float b3v = b3[0];

    // swizzled read offsets (lane constants): global chunk c=2j+h of row r
    // lives at LDS position (c - r) & 7
    int soff[4], doff[4];
    #pragma unroll
    for (int j = 0; j < 4; ++j) {
        soff[j] = et * 256       + (((2 * j + h - 2 * et)     & 7) << 4);
        doff[j] = et * 256 + 128 + (((2 * j + h - 2 * et - 1) & 7) << 4);
    }

    const int nGroups    = (nEdges + 7) >> 3;    // 8-edge groups (2 tiles)
    const int totalWaves = gridDim.x * 4;
    int g = blockIdx.x * 4 + wid;
    if (g >= nGroups) return;

    char* base0 = (char*)&smem[wid][0][0][0];
    char* base1 = (char*)&smem[wid][1][0][0];

    // issue one group's 2 tile-loads (1KB each) into the given buffer
#define ISSUE(VS, VD, BUF) do { \
    _Pragma("unroll") \
    for (int p_ = 0; p_ < 2; ++p_) { \
        const int si_  = __shfl((VS), 4 * p_ + eloc); \
        const int di_  = __shfl((VD), 4 * p_ + eloc); \
        const int idx_ = endp ? di_ : si_; \
        const char* ga_ = (const char*)feat16 \
                        + (size_t)(unsigned)idx_ * 128u + gchunk * 16; \
        __builtin_amdgcn_global_load_lds( \
            (const __attribute__((address_space(1))) void*)ga_, \
            (__attribute__((address_space(3))) void*)((BUF) + p_ * 1024), \
            16, 0, 0); \
    } \
} while (0)

    // prologue
    int ce = min(g * 8 + (l & 7), nEdges - 1);
    int vs = edge_index[ce];
    int vd = edge_index[nEdges + ce];
    ISSUE(vs, vd, base0);

    int gn = g + totalWaves;
    int vs1 = 0, vd1 = 0;
    if (gn < nGroups) {
        const int cen = min(gn * 8 + (l & 7), nEdges - 1);
        vs1 = edge_index[cen];
        vd1 = edge_index[nEdges + cen];
    }

    int cur = 0;
    while (true) {
        const bool more = (gn < nGroups);

        if (more) {
            ISSUE(vs1, vd1, (cur ? base0 : base1));
            __builtin_amdgcn_sched_barrier(0);
            asm volatile("s_waitcnt vmcnt(2)" ::: "memory");
        } else {
            asm volatile("s_waitcnt vmcnt(0)" ::: "memory");
        }
        __builtin_amdgcn_sched_barrier(0);

        const int g2 = gn + totalWaves;
        int vs2 = 0, vd2 = 0;
        if (g2 < nGroups) {
            const int ce2 = min(g2 * 8 + (l & 7), nEdges - 1);
            vs2 = edge_index[ce2];
            vd2 = edge_index[nEdges + ce2];
        }

        // ---- phase 1: 2 tiles x {4 k-steps of conv + MFMA, in-lane fc2} ----
        const char* myBuf = cur ? base1 : base0;
        float zp[2];
        #pragma unroll
        for (int t = 0; t < 2; ++t) {
            const char* pb = myBuf + t * 1024;
            f32x16 acc = accInit;              // b1 pre-loaded in C
            #pragma unroll
            for (int j = 0; j < 4; ++j) {
                U8 s_, d_, c_;
                s_.v = *(const f16x8*)(pb + soff[j]);
                d_.v = *(const f16x8*)(pb + doff[j]);
                #pragma unroll
                for (int pp = 0; pp < 4; ++pp) {
                    f16x2 tt = __builtin_elementwise_fma(vca, s_.p[pp],
                                __builtin_elementwise_fma(vcc, d_.p[pp], vcb));
                    c_.p[pp] = __builtin_elementwise_max(tt, vzero);
                }
                acc = __builtin_amdgcn_mfma_f32_32x32x16_f16(aw[j], c_.v, acc, 0, 0, 0);
            }
            float z_ = 0.f;
            #pragma unroll
            for (int r = 0; r < 8; ++r) {
                const float h1 = fmaxf(acc[r], 0.f);   // bias already in
                z_ = fmaf(h1, w2r[r], z_);
            }
            zp[t] = z_;
        }

        // ---- phase 2: epilogue — xor32 on DS; rest on VALU via DPP ---------
        #pragma unroll
        for (int t = 0; t < 2; ++t) zp[t] += __shfl_xor(zp[t], 32);
        #pragma unroll
        for (int t = 0; t < 2; ++t) zp[t] = fmaxf(zp[t] + b2v, 0.f) * w3v;
        #pragma unroll
        for (int t = 0; t < 2; ++t) zp[t] = dpp_xadd<0xB1>(zp[t]);   // + lane^1
        #pragma unroll
        for (int t = 0; t < 2; ++t) zp[t] = dpp_xadd<0x4E>(zp[t]);   // + lane^2
        #pragma unroll
        for (int t = 0; t < 2; ++t) zp[t] = dpp_xadd<0x141>(zp[t]);  // + other quad
        #pragma unroll
        for (int t = 0; t < 2; ++t) {
            const float z  = zp[t] + b3v;
            const float sg = 1.0f / (1.0f + __expf(-z));
            if ((l & 39) == 0) {                  // lanes 0,8,16,24 (h=0,ch=0)
                const int e = g * 8 + t * 4 + et;
                if (e < nEdges) out[e] = sg;
            }
        }

        if (!more) break;
        g = gn; gn = g2; vs1 = vs2; vd1 = vd2; cur ^= 1;
    }
#undef ISSUE
}

// ------------------- fallback: round-4 bf16 kernel (proven) ----------------
__global__ __launch_bounds__(256) void edgeconv_mfma2(
    const float* __restrict__ features, const int* __restrict__ edge_index,
    const float* __restrict__ conv_w, const float* __restrict__ conv_b,
    const float* __restrict__ w1, const float* __restrict__ b1,
    const float* __restrict__ w2, const float* __restrict__ b2,
    const float* __restrict__ w3, const float* __restrict__ b3,
    float* __restrict__ out, int nEdges)
{
    const int tid = threadIdx.x;
    const int l   = tid & 63;
    const int wid = tid >> 6;
    const int grp = l >> 4;
    const int n   = l & 15;
    const int ch  = l & 7;
    const int el  = (l >> 3) & 1;

    const float* w1r = w1 + n * 64 + grp * 8;
    bf16x8 aw0, aw1;
    #pragma unroll
    for (int i = 0; i < 8; ++i) {
        aw0[i] = f2bf(w1r[i]);
        aw1[i] = f2bf(w1r[32 + i]);
    }
    const float ca = conv_w[2 * ch];
    const float cc = conv_w[2 * ch + 1];
    const float cb = conv_b[ch];
    float b1r[4], w2r[4];
    #pragma unroll
    for (int r = 0; r < 4; ++r) { b1r[r] = b1[grp * 4 + r]; w2r[r] = w2[grp * 4 + r]; }
    const float w3v = w3[ch];
    const float b2v = b2[0];
    const float b3v = b3[0];

    const int ebase = (blockIdx.x * 4 + wid) * 16;
    const int ce    = min(ebase + n, nEdges - 1);
    const int vs    = edge_index[ce];
    const int vd    = edge_index[nEdges + ce];

#define LOAD_TILE4(T, X1, X2) do { \
    const int sn_ = __shfl(vs, 2 * (T) + el); \
    const int dn_ = __shfl(vd, 2 * (T) + el); \
    const float* p1_ = features + (size_t)sn_ * 64 + grp * 8; \
    const float* p2_ = features + (size_t)dn_ * 64 + grp * 8; \
    X1[0] = *(const f32x4*)(p1_);      X1[1] = *(const f32x4*)(p1_ + 4); \
    X1[2] = *(const f32x4*)(p1_ + 32); X1[3] = *(const f32x4*)(p1_ + 36); \
    X2[0] = *(const f32x4*)(p2_);      X2[1] = *(const f32x4*)(p2_ + 4); \
    X2[2] = *(const f32x4*)(p2_ + 32); X2[3] = *(const f32x4*)(p2_ + 36); \
} while (0)

    f32x4 x1v[4], x2v[4];
    LOAD_TILE4(0, x1v, x2v);
    const f32x2 vca = {ca, ca}, vcc = {cc, cc}, vcb = {cb, cb};
    const f32x2 vz  = {0.f, 0.f};

    #pragma unroll
    for (int t = 0; t < 8; ++t) {
        f32x4 n1v[4], n2v[4];
        if (t < 7) LOAD_TILE4(t + 1, n1v, n2v);
        bf16x8 cf0, cf1;
        #pragma unroll
        for (int p = 0; p < 8; ++p) {
            const int q = p >> 1;
            const int o = (p & 1) * 2;
            f32x2 u = {x1v[q][o], x1v[q][o + 1]};
            f32x2 v = {x2v[q][o], x2v[q][o + 1]};
            f32x2 tt = __builtin_elementwise_fma(vca, u,
                        __builtin_elementwise_fma(vcc, v, vcb));
            tt = __builtin_elementwise_max(tt, vz);
            const short s0 = f2bf(tt[0]), s1 = f2bf(tt[1]);
            if (p < 4) { cf0[2 * (p & 3)] = s0; cf0[2 * (p & 3) + 1] = s1; }
            else       { cf1[2 * (p & 3)] = s0; cf1[2 * (p & 3) + 1] = s1; }
        }
        f32x4 acc = {0.f, 0.f, 0.f, 0.f};
        acc = __builtin_amdgcn_mfma_f32_16x16x32_bf16(aw0, cf0, acc, 0, 0, 0);
        acc = __builtin_amdgcn_mfma_f32_16x16x32_bf16(aw1, cf1, acc, 0, 0, 0);
        float zp = 0.f;
        #pragma unroll
        for (int r = 0; r < 4; ++r) {
            const float h1 = fmaxf(acc[r] + b1r[r], 0.f);
            zp = fmaf(h1, w2r[r], zp);
        }
        zp += __shfl_xor(zp, 16);
        zp += __shfl_xor(zp, 32);
        const float h2 = fmaxf(zp + b2v, 0.f);
        float t3 = h2 * w3v;
        t3 += __shfl_xor(t3, 1);
        t3 += __shfl_xor(t3, 2);
        t3 += __shfl_xor(t3, 4);
        const float z  = t3 + b3v;
        const float sg = 1.0f / (1.0f + __expf(-z));
        if ((l & 55) == 0) {
            const int e = ebase + 2 * t + (l >> 3);
            if (e < nEdges) out[e] = sg;
        }
        if (t < 7) {
            #pragma unroll
            for (int i = 0; i < 4; ++i) { x1v[i] = n1v[i]; x2v[i] = n2v[i]; }
        }
    }
#undef LOAD_TILE4
}

extern "C" void kernel_launch(void* const* d_in, const int* in_sizes, int n_in,
                              void* d_out, int out_size, void* d_ws, size_t ws_size,
                              hipStream_t stream) {
    // 0:x 1:features 2:edge_index 3:conv_w 4:conv_b 5:w1 6:b1 7:w2 8:b2 9:w3 10:b3
    const float* features = (const float*)d_in[1];
    const int*   edge_idx = (const int*)d_in[2];
    const float* conv_w   = (const float*)d_in[3];
    const float* conv_b   = (const float*)d_in[4];
    const float* w1       = (const float*)d_in[5];
    const float* b1       = (const float*)d_in[6];
    const float* w2       = (const float*)d_in[7];
    const float* b2       = (const float*)d_in[8];
    const float* w3       = (const float*)d_in[9];
    const float* b3       = (const float*)d_in[10];
    float*       out      = (float*)d_out;

    const int nEdges = in_sizes[2] / 2;          // (2, E)
    const int nFeat  = in_sizes[1];              // 50000*64

    const size_t need = (size_t)nFeat * sizeof(_Float16);
    if (ws_size >= need) {
        _Float16* feat16 = (_Float16*)d_ws;
        feat_to_f16<<<2048, 256, 0, stream>>>(features, feat16, nFeat / 4);
        // 4-wave bucket -> 4 blocks/CU x 256 CU = 1024 blocks
        const int nGroups = (nEdges + 7) >> 3;
        const int blocks  = min(1024, (nGroups + 3) / 4);
        edgeconv_f16_m32e<<<blocks, 256, 0, stream>>>(feat16, edge_idx,
                                                      conv_w, conv_b, w1, b1, w2, b2, w3, b3,
                                                      out, nEdges);
    } else {
        const dim3 grid((nEdges + 63) / 64);
        edgeconv_mfma2<<<grid, 256, 0, stream>>>(features, edge_idx,
                                                 conv_w, conv_b, w1, b1, w2, b2, w3, b3,
                                                 out, nEdges);
    }
}

// Round 22
// 71.275 us; speedup vs baseline: 1.0293x; 1.0293x over previous
//
#include <hip/hip_runtime.h>
#include <hip/hip_bf16.h>

// ---------------------------------------------------------------------------
// EdgeConvNet — Round 22: explicit v_pk_fma_f16/v_pk_max_f16 conv (codegen test).
//
// R21 flat at 70.3us. Model mismatch: source-level VALU count predicts ~19%
// VALUBusy; measured 59% -> compiler emits ~3x the VALU work. Largest
// candidate sink: __builtin_elementwise_fma/max on f16x2 scalarizing instead
// of lowering to VOP3P packed ops. R22 replaces ONLY the conv inner math
// with explicit inline-asm v_pk_fma_f16 x2 + v_pk_max_f16 per f16-pair, on
// raw uint bit-patterns from uint4 LDS reads. Everything else byte-identical
// to R21 (swizzled GLDS dbuf, 32x32x16 MFMA bias-in-C, DPP epilogue,
// persistent 1024 blocks, (256,4)).
// Pre-committed read: win -> scalarization confirmed; flat -> co-limited
// equilibrium confirmed, declare roofline.
// ---------------------------------------------------------------------------

typedef _Float16 f16x8 __attribute__((ext_vector_type(8)));
typedef _Float16 f16x4 __attribute__((ext_vector_type(4)));
typedef _Float16 f16x2 __attribute__((ext_vector_type(2)));
typedef short    bf16x8 __attribute__((ext_vector_type(8)));
typedef float    f32x4  __attribute__((ext_vector_type(4)));
typedef float    f32x2  __attribute__((ext_vector_type(2)));
typedef float    f32x16 __attribute__((ext_vector_type(16)));

union UV { uint4 u; f16x8 v; };

static __device__ __forceinline__ short f2bf(float f) {
    union { __hip_bfloat16 h; short s; } u;
    u.h = __float2bfloat16(f);
    return u.s;
}

// packed conv: relu(ca*s + cc*d + cb) on 2 f16 lanes, guaranteed VOP3P.
static __device__ __forceinline__ unsigned pk_conv(unsigned s, unsigned d,
                                                   unsigned ca, unsigned cc,
                                                   unsigned cb, unsigned z) {
    unsigned t, r;
    asm("v_pk_fma_f16 %0, %1, %2, %3" : "=v"(t) : "v"(cc), "v"(d), "v"(cb));
    asm("v_pk_fma_f16 %0, %1, %2, %0" : "+v"(t) : "v"(ca), "v"(s));
    asm("v_pk_max_f16 %0, %1, %2" : "=v"(r) : "v"(t), "v"(z));
    return r;
}

// DPP cross-lane add on the VALU pipe.
template <int CTRL>
static __device__ __forceinline__ float dpp_xadd(float x) {
    union { float f; int i; } u, r;
    u.f = x;
    r.i = __builtin_amdgcn_mov_dpp(u.i, CTRL, 0xF, 0xF, false);
    return x + r.f;
}

// ---------------------------- pre-pass ------------------------------------
__global__ __launch_bounds__(256) void feat_to_f16(const float* __restrict__ in,
                                                   _Float16* __restrict__ out,
                                                   int n4) {
    int i = blockIdx.x * blockDim.x + threadIdx.x;
    const int stride = gridDim.x * blockDim.x;
    for (; i < n4; i += stride) {
        const f32x4 v = ((const f32x4*)in)[i];
        ((f16x4*)out)[i] = __builtin_convertvector(v, f16x4);
    }
}

// ------ main (persistent, 32x32 MFMA, swizzled dbuf GLDS staging) ----------
__global__ __launch_bounds__(256, 4) void edgeconv_f16_pk(
    const _Float16* __restrict__ feat16,     // (50000, 64) f16 (in d_ws)
    const int*      __restrict__ edge_index, // (2, E) int32
    const float* __restrict__ conv_w, const float* __restrict__ conv_b,
    const float* __restrict__ w1,     const float* __restrict__ b1,
    const float* __restrict__ w2,     const float* __restrict__ b2,
    const float* __restrict__ w3,     const float* __restrict__ b3,
    float* __restrict__ out, int nEdges)
{
    // per-wave staging: [wave][buf][tile][1KB]; tile = 4 edges = 8 rows x 128B
    // row r = edge_local*2 + endpoint; LDS chunk position p holds GLOBAL
    // chunk (p + r) & 7 (swizzled source; LDS dest linear per m104)
    __shared__ __align__(16) char smem[4][2][2][1024];

    const int tid = threadIdx.x;
    const int l   = tid & 63;
    const int wid = tid >> 6;
    const int n   = l & 31;        // A row = g ; B col = et*8 + ch
    const int h   = l >> 5;        // k-half (8 elems each, K=16)
    const int ch  = n & 7;
    const int et  = n >> 3;        // edge within 4-edge tile
    // loader-side lane decomposition (1KB tile load)
    const int chunk  = l & 7;      // LDS chunk position within a 128B row
    const int rr     = l >> 3;     // row 0..7
    const int eloc   = rr >> 1;    // edge within tile
    const int endp   = rr & 1;     // 0=src 1=dst
    const int gchunk = (chunk + rr) & 7;   // swizzled GLOBAL chunk to fetch

    // A fragments: w1[g=n][k], k = j*16 + h*8 + i; rows 16..31 = 0 (R6-proven)
    f16x8 aw[4];
    #pragma unroll
    for (int j = 0; j < 4; ++j)
        #pragma unroll
        for (int i = 0; i < 8; ++i) aw[j][i] = (_Float16)0.f;
    if (n < 16) {
        const float* w1r = w1 + n * 64 + h * 8;
        #pragma unroll
        for (int j = 0; j < 4; ++j)
            #pragma unroll
            for (int i = 0; i < 8; ++i) aw[j][i] = (_Float16)w1r[j * 16 + i];
    }

    // conv params as packed-f16 splats (raw 32-bit patterns)
    union { f16x2 h2; unsigned u; } pca, pcc, pcb, pz;
    {
        const _Float16 cah = (_Float16)conv_w[2 * ch];
        const _Float16 cch = (_Float16)conv_w[2 * ch + 1];
        const _Float16 cbh = (_Float16)conv_b[ch];
        pca.h2 = (f16x2){cah, cah};
        pcc.h2 = (f16x2){cch, cch};
        pcb.h2 = (f16x2){cbh, cbh};
        pz.h2  = (f16x2){(_Float16)0.f, (_Float16)0.f};
    }
    const unsigned uca = pca.u, ucc = pcc.u, ucb = pcb.u, uz = pz.u;

    // fc1 bias folded into MFMA C-init: acc reg r<8 holds row g =
    // (r&3) + 8*(r>>2) + 4h ; regs 8..15 are the zero A-rows (ignored)
    f32x16 accInit = {};
    float w2r[8];
    #pragma unroll
    for (int r = 0; r < 4; ++r) {
        accInit[r]     = b1[4 * h + r];      w2r[r]     = w2[4 * h + r];
        accInit[4 + r] = b1[8 + 4 * h + r];  w2r[4 + r] = w2[8 + 4 * h + r];
    }
    const float w3v = w3[ch];
    const float b2v = b2[0];
    const float b3v = b3[0];

    // swizzled read offsets (lane constants): global chunk c=2j+h of row r
    // lives at LDS position (c - r) & 7
    int soff[4], doff[4];
    #pragma unroll
    for (int j = 0; j < 4; ++j) {
        soff[j] = et * 256       + (((2 * j + h - 2 * et)     & 7) << 4);
        doff[j] = et * 256 + 128 + (((2 * j + h - 2 * et - 1) & 7) << 4);
    }

    const int nGroups    = (nEdges + 7) >> 3;    // 8-edge groups (2 tiles)
    const int totalWaves = gridDim.x * 4;
    int g = blockIdx.x * 4 + wid;
    if (g >= nGroups) return;

    char* base0 = (char*)&smem[wid][0][0][0];
    char* base1 = (char*)&smem[wid][1][0][0];

    // issue one group's 2 tile-loads (1KB each) into the given buffer
#define ISSUE(VS, VD, BUF) do { \
    _Pragma("unroll") \
    for (int p_ = 0; p_ < 2; ++p_) { \
        const int si_  = __shfl((VS), 4 * p_ + eloc); \
        const int di_  = __shfl((VD), 4 * p_ + eloc); \
        const int idx_ = endp ? di_ : si_; \
        const char* ga_ = (const char*)feat16 \
                        + (size_t)(unsigned)idx_ * 128u + gchunk * 16; \
        __builtin_amdgcn_global_load_lds( \
            (const __attribute__((address_space(1))) void*)ga_, \
            (__attribute__((address_space(3))) void*)((BUF) + p_ * 1024), \
            16, 0, 0); \
    } \
} while (0)

    // prologue
    int ce = min(g * 8 + (l & 7), nEdges - 1);
    int vs = edge_index[ce];
    int vd = edge_index[nEdges + ce];
    ISSUE(vs, vd, base0);

    int gn = g + totalWaves;
    int vs1 = 0, vd1 = 0;
    if (gn < nGroups) {
        const int cen = min(gn * 8 + (l & 7), nEdges - 1);
        vs1 = edge_index[cen];
        vd1 = edge_index[nEdges + cen];
    }

    int cur = 0;
    while (true) {
        const bool more = (gn < nGroups);

        if (more) {
            ISSUE(vs1, vd1, (cur ? base0 : base1));
            __builtin_amdgcn_sched_barrier(0);
            asm volatile("s_waitcnt vmcnt(2)" ::: "memory");
        } else {
            asm volatile("s_waitcnt vmcnt(0)" ::: "memory");
        }
        __builtin_amdgcn_sched_barrier(0);

        const int g2 = gn + totalWaves;
        int vs2 = 0, vd2 = 0;
        if (g2 < nGroups) {
            const int ce2 = min(g2 * 8 + (l & 7), nEdges - 1);
            vs2 = edge_index[ce2];
            vd2 = edge_index[nEdges + ce2];
        }

        // ---- phase 1: 2 tiles x {4 k-steps of pk-conv + MFMA, in-lane fc2} -
        const char* myBuf = cur ? base1 : base0;
        float zp[2];
        #pragma unroll
        for (int t = 0; t < 2; ++t) {
            const char* pb = myBuf + t * 1024;
            f32x16 acc = accInit;              // b1 pre-loaded in C
            #pragma unroll
            for (int j = 0; j < 4; ++j) {
                const uint4 su = *(const uint4*)(pb + soff[j]);
                const uint4 du = *(const uint4*)(pb + doff[j]);
                UV c_;
                c_.u.x = pk_conv(su.x, du.x, uca, ucc, ucb, uz);
                c_.u.y = pk_conv(su.y, du.y, uca, ucc, ucb, uz);
                c_.u.z = pk_conv(su.z, du.z, uca, ucc, ucb, uz);
                c_.u.w = pk_conv(su.w, du.w, uca, ucc, ucb, uz);
                acc = __builtin_amdgcn_mfma_f32_32x32x16_f16(aw[j], c_.v, acc, 0, 0, 0);
            }
            float z_ = 0.f;
            #pragma unroll
            for (int r = 0; r < 8; ++r) {
                const float h1 = fmaxf(acc[r], 0.f);   // bias already in
                z_ = fmaf(h1, w2r[r], z_);
            }
            zp[t] = z_;
        }

        // ---- phase 2: epilogue — xor32 on DS; rest on VALU via DPP ---------
        #pragma unroll
        for (int t = 0; t < 2; ++t) zp[t] += __shfl_xor(zp[t], 32);
        #pragma unroll
        for (int t = 0; t < 2; ++t) zp[t] = fmaxf(zp[t] + b2v, 0.f) * w3v;
        #pragma unroll
        for (int t = 0; t < 2; ++t) zp[t] = dpp_xadd<0xB1>(zp[t]);   // + lane^1
        #pragma unroll
        for (int t = 0; t < 2; ++t) zp[t] = dpp_xadd<0x4E>(zp[t]);   // + lane^2
        #pragma unroll
        for (int t = 0; t < 2; ++t) zp[t] = dpp_xadd<0x141>(zp[t]);  // + other quad
        #pragma unroll
        for (int t = 0; t < 2; ++t) {
            const float z  = zp[t] + b3v;
            const float sg = 1.0f / (1.0f + __expf(-z));
            if ((l & 39) == 0) {                  // lanes 0,8,16,24 (h=0,ch=0)
                const int e = g * 8 + t * 4 + et;
                if (e < nEdges) out[e] = sg;
            }
        }

        if (!more) break;
        g = gn; gn = g2; vs1 = vs2; vd1 = vd2; cur ^= 1;
    }
#undef ISSUE
}

// ------------------- fallback: round-4 bf16 kernel (proven) ----------------
__global__ __launch_bounds__(256) void edgeconv_mfma2(
    const float* __restrict__ features, const int* __restrict__ edge_index,
    const float* __restrict__ conv_w, const float* __restrict__ conv_b,
    const float* __restrict__ w1, const float* __restrict__ b1,
    const float* __restrict__ w2, const float* __restrict__ b2,
    const float* __restrict__ w3, const float* __restrict__ b3,
    float* __restrict__ out, int nEdges)
{
    typedef float f32x2l __attribute__((ext_vector_type(2)));
    const int tid = threadIdx.x;
    const int l   = tid & 63;
    const int wid = tid >> 6;
    const int grp = l >> 4;
    const int n   = l & 15;
    const int ch  = l & 7;
    const int el  = (l >> 3) & 1;

    const float* w1r = w1 + n * 64 + grp * 8;
    bf16x8 aw0, aw1;
    #pragma unroll
    for (int i = 0; i < 8; ++i) {
        aw0[i] = f2bf(w1r[i]);
        aw1[i] = f2bf(w1r[32 + i]);
    }
    const float ca = conv_w[2 * ch];
    const float cc = conv_w[2 * ch + 1];
    const float cb = conv_b[ch];
    float b1r[4], w2r[4];
    #pragma unroll
    for (int r = 0; r < 4; ++r) { b1r[r] = b1[grp * 4 + r]; w2r[r] = w2[grp * 4 + r]; }
    const float w3v = w3[ch];
    const float b2v = b2[0];
    const float b3v = b3[0];

    const int ebase = (blockIdx.x * 4 + wid) * 16;
    const int ce    = min(ebase + n, nEdges - 1);
    const int vs    = edge_index[ce];
    const int vd    = edge_index[nEdges + ce];

#define LOAD_TILE4(T, X1, X2) do { \
    const int sn_ = __shfl(vs, 2 * (T) + el); \
    const int dn_ = __shfl(vd, 2 * (T) + el); \
    const float* p1_ = features + (size_t)sn_ * 64 + grp * 8; \
    const float* p2_ = features + (size_t)dn_ * 64 + grp * 8; \
    X1[0] = *(const f32x4*)(p1_);      X1[1] = *(const f32x4*)(p1_ + 4); \
    X1[2] = *(const f32x4*)(p1_ + 32); X1[3] = *(const f32x4*)(p1_ + 36); \
    X2[0] = *(const f32x4*)(p2_);      X2[1] = *(const f32x4*)(p2_ + 4); \
    X2[2] = *(const f32x4*)(p2_ + 32); X2[3] = *(const f32x4*)(p2_ + 36); \
} while (0)

    f32x4 x1v[4], x2v[4];
    LOAD_TILE4(0, x1v, x2v);
    const f32x2l vca = {ca, ca}, vcc = {cc, cc}, vcb = {cb, cb};
    const f32x2l vz  = {0.f, 0.f};

    #pragma unroll
    for (int t = 0; t < 8; ++t) {
        f32x4 n1v[4], n2v[4];
        if (t < 7) LOAD_TILE4(t + 1, n1v, n2v);
        bf16x8 cf0, cf1;
        #pragma unroll
        for (int p = 0; p < 8; ++p) {
            const int q = p >> 1;
            const int o = (p & 1) * 2;
            f32x2l u = {x1v[q][o], x1v[q][o + 1]};
            f32x2l v = {x2v[q][o], x2v[q][o + 1]};
            f32x2l tt = __builtin_elementwise_fma(vca, u,
                         __builtin_elementwise_fma(vcc, v, vcb));
            tt = __builtin_elementwise_max(tt, vz);
            const short s0 = f2bf(tt[0]), s1 = f2bf(tt[1]);
            if (p < 4) { cf0[2 * (p & 3)] = s0; cf0[2 * (p & 3) + 1] = s1; }
            else       { cf1[2 * (p & 3)] = s0; cf1[2 * (p & 3) + 1] = s1; }
        }
        f32x4 acc = {0.f, 0.f, 0.f, 0.f};
        acc = __builtin_amdgcn_mfma_f32_16x16x32_bf16(aw0, cf0, acc, 0, 0, 0);
        acc = __builtin_amdgcn_mfma_f32_16x16x32_bf16(aw1, cf1, acc, 0, 0, 0);
        float zp = 0.f;
        #pragma unroll
        for (int r = 0; r < 4; ++r) {
            const float h1 = fmaxf(acc[r] + b1r[r], 0.f);
            zp = fmaf(h1, w2r[r], zp);
        }
        zp += __shfl_xor(zp, 16);
        zp += __shfl_xor(zp, 32);
        const float h2 = fmaxf(zp + b2v, 0.f);
        float t3 = h2 * w3v;
        t3 += __shfl_xor(t3, 1);
        t3 += __shfl_xor(t3, 2);
        t3 += __shfl_xor(t3, 4);
        const float z  = t3 + b3v;
        const float sg = 1.0f / (1.0f + __expf(-z));
        if ((l & 55) == 0) {
            const int e = ebase + 2 * t + (l >> 3);
            if (e < nEdges) out[e] = sg;
        }
        if (t < 7) {
            #pragma unroll
            for (int i = 0; i < 4; ++i) { x1v[i] = n1v[i]; x2v[i] = n2v[i]; }
        }
    }
#undef LOAD_TILE4
}

extern "C" void kernel_launch(void* const* d_in, const int* in_sizes, int n_in,
                              void* d_out, int out_size, void* d_ws, size_t ws_size,
                              hipStream_t stream) {
    // 0:x 1:features 2:edge_index 3:conv_w 4:conv_b 5:w1 6:b1 7:w2 8:b2 9:w3 10:b3
    const float* features = (const float*)d_in[1];
    const int*   edge_idx = (const int*)d_in[2];
    const float* conv_w   = (const float*)d_in[3];
    const float* conv_b   = (const float*)d_in[4];
    const float* w1       = (const float*)d_in[5];
    const float* b1       = (const float*)d_in[6];
    const float* w2       = (const float*)d_in[7];
    const float* b2       = (const float*)d_in[8];
    const float* w3       = (const float*)d_in[9];
    const float* b3       = (const float*)d_in[10];
    float*       out      = (float*)d_out;

    const int nEdges = in_sizes[2] / 2;          // (2, E)
    const int nFeat  = in_sizes[1];              // 50000*64

    const size_t need = (size_t)nFeat * sizeof(_Float16);
    if (ws_size >= need) {
        _Float16* feat16 = (_Float16*)d_ws;
        feat_to_f16<<<2048, 256, 0, stream>>>(features, feat16, nFeat / 4);
        // 4-wave bucket -> 4 blocks/CU x 256 CU = 1024 blocks
        const int nGroups = (nEdges + 7) >> 3;
        const int blocks  = min(1024, (nGroups + 3) / 4);
        edgeconv_f16_pk<<<blocks, 256, 0, stream>>>(feat16, edge_idx,
                                                    conv_w, conv_b, w1, b1, w2, b2, w3, b3,
                                                    out, nEdges);
    } else {
        const dim3 grid((nEdges + 63) / 64);
        edgeconv_mfma2<<<grid, 256, 0, stream>>>(features, edge_idx,
                                                 conv_w, conv_b, w1, b1, w2, b2, w3, b3,
                                                 out, nEdges);
    }
}